// Round 5
// baseline (100.488 us; speedup 1.0000x reference)
//
#include <hip/hip_runtime.h>
#include <math.h>

#define B_ 4
#define T_ 512
#define D_ 128
#define H_ 64
#define DEMO_ 12
#define LOG2E 1.4426950408889634f
#define SC2   (2.0f * LOG2E)          // fold tanh's 2x and the exp2 conversion

typedef float float2v __attribute__((ext_vector_type(2)));

// ---- kernel 1: Q' = (input@Wt)*SC2 [B*T,H]; K2T' = ((input@Wx)+demo@Wd+bh)*SC2 [B,H,T]
//      block 0 also emits Cs = (ba + sum Wa) * LOG2E.
__global__ __launch_bounds__(256) void prep_kernel(
    const float* __restrict__ input, const float* __restrict__ demo,
    const float* __restrict__ Wt, const float* __restrict__ Wx,
    const float* __restrict__ Wd, const float* __restrict__ bh,
    const float* __restrict__ Wa, const float* __restrict__ ba,
    float* __restrict__ Q, float* __restrict__ K2T, float* __restrict__ Cs)
{
    __shared__ float in_sh[8 * D_];
    int tid  = threadIdx.x;
    int row0 = blockIdx.x * 8;          // global row = b*T + t (8 rows never straddle b)
    int b    = row0 >> 9;               // T_ == 512

    #pragma unroll
    for (int k = 0; k < 4; ++k)
        in_sh[tid + 256 * k] = input[row0 * D_ + tid + 256 * k];
    __syncthreads();

    int h  = tid & 63;
    int rr = tid >> 6;                  // 0..3 ; each thread does rows rr and rr+4

    float dB = bh[h];
    #pragma unroll
    for (int kk = 0; kk < DEMO_; ++kk)
        dB = fmaf(demo[b * DEMO_ + kk], Wd[kk * H_ + h], dB);

    float q0 = 0.f, q1 = 0.f, x0 = 0.f, x1 = 0.f;
    #pragma unroll 8
    for (int k = 0; k < D_; ++k) {
        float wt = Wt[k * H_ + h];
        float wx = Wx[k * H_ + h];
        float a0 = in_sh[rr * D_ + k];
        float a1 = in_sh[(rr + 4) * D_ + k];
        q0 = fmaf(a0, wt, q0);
        q1 = fmaf(a1, wt, q1);
        x0 = fmaf(a0, wx, x0);
        x1 = fmaf(a1, wx, x1);
    }

    int ra = row0 + rr, rb = row0 + rr + 4;
    Q[ra * H_ + h] = q0 * SC2;
    Q[rb * H_ + h] = q1 * SC2;
    int ta = ra & (T_ - 1), tb = rb & (T_ - 1);
    K2T[(b * H_ + h) * T_ + ta] = (x0 + dB) * SC2;
    K2T[(b * H_ + h) * T_ + tb] = (x1 + dB) * SC2;

    if (blockIdx.x == 0 && tid < 64) {
        float w = Wa[tid];
        #pragma unroll
        for (int off = 32; off; off >>= 1) w += __shfl_down(w, off, 64);
        if (tid == 0) Cs[0] = (ba[0] + w) * LOG2E;
    }
}

// ---- kernel 2: causal-only scores + softmax + v -----------------------------
// grid (256, B); block = 512 threads = 8 waves; block owns rows {2y, 2y+1}
// where y = (bx&7)*32 + (bx>>3)  (swizzle: every 8 consecutive blocks have
// equal total triangular work). Thread j only computes columns j <= i
// (pre-mask rowmax cancels in p/(s+1e-7) -> causal max is equivalent).
__global__ __launch_bounds__(512, 8) void attn_kernel(
    const float* __restrict__ input,
    const float* __restrict__ Qs, const float* __restrict__ K2T,
    const float* __restrict__ Wa, const float* __restrict__ Cs,
    float* __restrict__ out_v, float* __restrict__ out_e)
{
    __shared__ float p_sh[T_ * 2];        // [j][r]
    __shared__ float red_m[8 * 2];        // [wave][r]
    __shared__ float red_s[8 * 2];
    __shared__ float partial[4][2 * D_];  // [s4][r*128+d]

    int tid  = threadIdx.x;
    int bx   = blockIdx.x;
    int b    = blockIdx.y;
    int y    = ((bx & 7) << 5) | (bx >> 3);   // [0,256) bijective
    int i0   = 2 * y, i1 = i0 + 1;
    int lane = tid & 63, wv = tid >> 6;
    int j    = tid;

    const float* qr0 = Qs + (size_t)(b * T_ + i0) * H_;   // uniform -> s_load
    const float* qr1 = qr0 + H_;
    const float* k2p = K2T + (size_t)b * H_ * T_ + j;
    float CL = Cs[0];

    float eg0 = -INFINITY, eg1 = -INFINITY;
    if ((wv << 6) <= i1) {                // wave-uniform: this wave has work
        float acc0 = 0.f, acc1 = 0.f;
        #pragma unroll 2
        for (int h0 = 0; h0 < H_; h0 += 8) {
            float kv[8];
            #pragma unroll
            for (int u = 0; u < 8; ++u)
                kv[u] = k2p[(size_t)(h0 + u) * T_];
            #pragma unroll
            for (int u = 0; u < 8; ++u) {
                float wa = Wa[h0 + u];                    // s_load (hoisted)
                float q0 = qr0[h0 + u], q1 = qr1[h0 + u]; // s_load (hoisted)
                float ex0 = __builtin_amdgcn_exp2f(q0 + kv[u]);
                float ex1 = __builtin_amdgcn_exp2f(q1 + kv[u]);
                acc0 = fmaf(wa, __builtin_amdgcn_rcpf(1.0f + ex0), acc0);
                acc1 = fmaf(wa, __builtin_amdgcn_rcpf(1.0f + ex1), acc1);
            }
        }
        if (j <= i0) eg0 = fmaf(-2.0f * LOG2E, acc0, CL);
        if (j <= i1) eg1 = fmaf(-2.0f * LOG2E, acc1, CL);
    }

    // row max over causal columns (cancels vs reference's global max)
    float M0 = eg0, M1 = eg1;
    #pragma unroll
    for (int off = 32; off; off >>= 1) {
        M0 = fmaxf(M0, __shfl_down(M0, off, 64));
        M1 = fmaxf(M1, __shfl_down(M1, off, 64));
    }
    if (lane == 0) ((float2v*)red_m)[wv] = (float2v){M0, M1};
    __syncthreads();                      // B1
    {
        float2v m = ((float2v*)red_m)[0];
        #pragma unroll
        for (int w = 1; w < 8; ++w) {
            float2v mw = ((float2v*)red_m)[w];
            m[0] = fmaxf(m[0], mw[0]);
            m[1] = fmaxf(m[1], mw[1]);
        }
        M0 = m[0]; M1 = m[1];
    }

    float p0 = (j <= i0) ? __builtin_amdgcn_exp2f(eg0 - M0) : 0.0f;
    float p1 = (j <= i1) ? __builtin_amdgcn_exp2f(eg1 - M1) : 0.0f;
    *(float2v*)&p_sh[j * 2] = (float2v){p0, p1};
    float S0 = p0, S1 = p1;
    #pragma unroll
    for (int off = 32; off; off >>= 1) {
        S0 += __shfl_down(S0, off, 64);
        S1 += __shfl_down(S1, off, 64);
    }
    if (lane == 0) ((float2v*)red_s)[wv] = (float2v){S0, S1};
    __syncthreads();                      // B2 (covers red_s and p_sh)

    float inv0, inv1;
    {
        float2v s = ((float2v*)red_s)[0];
        #pragma unroll
        for (int w = 1; w < 8; ++w) {
            float2v sw = ((float2v*)red_s)[w];
            s[0] += sw[0]; s[1] += sw[1];
        }
        inv0 = __builtin_amdgcn_rcpf(s[0] + 1e-7f);
        inv1 = __builtin_amdgcn_rcpf(s[1] + 1e-7f);
    }

    out_e[((size_t)(b * T_ + i0)) * T_ + j] = p0 * inv0;  // 0 for masked j
    out_e[((size_t)(b * T_ + i1)) * T_ + j] = p1 * inv1;

    // v[i_r, d] = inv_r * sum_{j<=i_r} p_r[j] * input[b,j,d] ; 4-way split on j
    {
        int d  = tid & 127;
        int s4 = tid >> 7;                // wave-uniform
        float va0 = 0.f, va1 = 0.f;
        if ((s4 << 7) <= i1) {            // skip chunks fully past the diagonal
            const float* inp = input + ((size_t)(b * T_) + (s4 << 7)) * D_ + d;
            const float* pp  = p_sh + (s4 << 7) * 2;
            #pragma unroll 4
            for (int jj = 0; jj < 128; ++jj) {
                float x = inp[(size_t)jj * D_];
                float2v p2 = *(const float2v*)&pp[jj * 2];
                va0 = fmaf(p2[0], x, va0);
                va1 = fmaf(p2[1], x, va1);
            }
        }
        partial[s4][d]      = va0;
        partial[s4][D_ + d] = va1;
    }
    __syncthreads();                      // B3

    if (tid < 256) {
        int r  = tid >> 7;                // 0/1
        int dd = tid & 127;
        float v = partial[0][r * D_ + dd] + partial[1][r * D_ + dd]
                + partial[2][r * D_ + dd] + partial[3][r * D_ + dd];
        float inv = r ? inv1 : inv0;
        out_v[(size_t)(b * T_ + i0 + r) * D_ + dd] = v * inv;
    }
}

extern "C" void kernel_launch(void* const* d_in, const int* in_sizes, int n_in,
                              void* d_out, int out_size, void* d_ws, size_t ws_size,
                              hipStream_t stream)
{
    const float* input = (const float*)d_in[0];
    const float* demo  = (const float*)d_in[1];
    const float* Wt    = (const float*)d_in[2];
    const float* Wx    = (const float*)d_in[3];
    const float* Wd    = (const float*)d_in[4];
    const float* bh    = (const float*)d_in[5];
    const float* Wa    = (const float*)d_in[6];
    const float* ba    = (const float*)d_in[7];

    float* out_v = (float*)d_out;                     // [B,T,D]
    float* out_e = out_v + (size_t)B_ * T_ * D_;      // [B,T,T]

    float* Q   = (float*)d_ws;                        // [B*T, H]  (pre-scaled)
    float* K2T = Q + (size_t)B_ * T_ * H_;            // [B, H, T] (pre-scaled)
    float* Cs  = K2T + (size_t)B_ * H_ * T_;          // [1]

    prep_kernel<<<dim3(B_ * T_ / 8), 256, 0, stream>>>(input, demo, Wt, Wx, Wd, bh,
                                                       Wa, ba, Q, K2T, Cs);
    attn_kernel<<<dim3(256, B_), 512, 0, stream>>>(input, Q, K2T, Wa, Cs, out_v, out_e);
}

// Round 6
// 92.712 us; speedup vs baseline: 1.0839x; 1.0839x over previous
//
#include <hip/hip_runtime.h>
#include <math.h>

#define B_ 4
#define T_ 512
#define D_ 128
#define H_ 64
#define DEMO_ 12
#define LOG2E 1.4426950408889634f
#define SC2   (2.0f * LOG2E)          // fold tanh's 2x and the exp2 conversion

typedef float float4v __attribute__((ext_vector_type(4)));
typedef float float2v __attribute__((ext_vector_type(2)));

// ---- kernel 1: Q' = (input@Wt)*SC2 [B*T,H]; K2T' = ((input@Wx)+demo@Wd+bh)*SC2 [B,H,T]
__global__ __launch_bounds__(256) void prep_kernel(
    const float* __restrict__ input, const float* __restrict__ demo,
    const float* __restrict__ Wt, const float* __restrict__ Wx,
    const float* __restrict__ Wd, const float* __restrict__ bh,
    const float* __restrict__ Wa, const float* __restrict__ ba,
    float* __restrict__ Q, float* __restrict__ K2T, float* __restrict__ Cs)
{
    __shared__ float in_sh[8 * D_];
    int tid  = threadIdx.x;
    int row0 = blockIdx.x * 8;
    int b    = row0 >> 9;               // T_ == 512

    #pragma unroll
    for (int k = 0; k < 4; ++k)
        in_sh[tid + 256 * k] = input[row0 * D_ + tid + 256 * k];
    __syncthreads();

    int h  = tid & 63;
    int rr = tid >> 6;

    float dB = bh[h];
    #pragma unroll
    for (int kk = 0; kk < DEMO_; ++kk)
        dB = fmaf(demo[b * DEMO_ + kk], Wd[kk * H_ + h], dB);

    float q0 = 0.f, q1 = 0.f, x0 = 0.f, x1 = 0.f;
    #pragma unroll 8
    for (int k = 0; k < D_; ++k) {
        float wt = Wt[k * H_ + h];
        float wx = Wx[k * H_ + h];
        float a0 = in_sh[rr * D_ + k];
        float a1 = in_sh[(rr + 4) * D_ + k];
        q0 = fmaf(a0, wt, q0);
        q1 = fmaf(a1, wt, q1);
        x0 = fmaf(a0, wx, x0);
        x1 = fmaf(a1, wx, x1);
    }

    int ra = row0 + rr, rb = row0 + rr + 4;
    Q[ra * H_ + h] = q0 * SC2;
    Q[rb * H_ + h] = q1 * SC2;
    int ta = ra & (T_ - 1), tb = rb & (T_ - 1);
    K2T[(b * H_ + h) * T_ + ta] = (x0 + dB) * SC2;
    K2T[(b * H_ + h) * T_ + tb] = (x1 + dB) * SC2;

    if (blockIdx.x == 0 && tid < 64) {
        float w = Wa[tid];
        #pragma unroll
        for (int off = 32; off; off >>= 1) w += __shfl_down(w, off, 64);
        if (tid == 0) Cs[0] = (ba[0] + w) * LOG2E;
    }
}

// ---- kernel 2: causal scores + softmax + v, UNIFORM-WORK blocks -------------
// grid (128, B); 512 threads = 8 waves. Block y owns rows {2y,2y+1} (A) and
// {510-2y,511-2y} (B): total causal work = 1026 row-cols for EVERY block.
// Q rows staged in LDS (one ds_read_b128 per h serves 4 rows); Wa via s_load.
__global__ __launch_bounds__(512, 4) void attn_kernel(
    const float* __restrict__ input,
    const float* __restrict__ Qs, const float* __restrict__ K2T,
    const float* __restrict__ Wa, const float* __restrict__ Cs,
    float* __restrict__ out_v, float* __restrict__ out_e)
{
    __shared__ float   qsh[H_ * 4];       // [h][r]
    __shared__ float   p_sh[T_ * 4];      // [j][r]  (unnormalized, masked)
    __shared__ float4v red_m[8];          // [wave]
    __shared__ float4v red_s[8];
    __shared__ float   partial[16][4 * D_]; // [s][r*128+d]

    int tid  = threadIdx.x;
    int y    = blockIdx.x;                // [0,128)
    int b    = blockIdx.y;
    int lane = tid & 63, wv = tid >> 6;
    int j    = tid;
    int iA0  = 2 * y,       iA1 = iA0 + 1;
    int iB0  = 510 - 2 * y, iB1 = iB0 + 1;

    if (tid < 256) {                      // qsh[h*4+r] = Q'[i_r, h]
        int h  = tid >> 2, r = tid & 3;
        int ir = (r < 2) ? (iA0 + r) : (iB0 + r - 2);
        qsh[tid] = Qs[(size_t)(b * T_ + ir) * H_ + h];
    }
    __syncthreads();                      // B0

    const float* k2p = K2T + (size_t)b * H_ * T_ + j;
    float CL   = Cs[0];
    bool  actA = (wv << 6) <= iA1;        // actA implies actB (iA1 < iB1)
    bool  actB = (wv << 6) <= iB1;

    float aA0 = 0.f, aA1 = 0.f, aB0 = 0.f, aB1 = 0.f;
    if (actA) {                           // 4-row h-loop
        #pragma unroll 2
        for (int h0 = 0; h0 < H_; h0 += 8) {
            float kv[8];
            #pragma unroll
            for (int u = 0; u < 8; ++u) kv[u] = k2p[(size_t)(h0 + u) * T_];
            #pragma unroll
            for (int u = 0; u < 8; ++u) {
                float wa   = Wa[h0 + u];                        // s_load
                float4v q4 = *(const float4v*)&qsh[(h0 + u) * 4];
                float e0 = __builtin_amdgcn_exp2f(q4[0] + kv[u]);
                float e1 = __builtin_amdgcn_exp2f(q4[1] + kv[u]);
                float e2 = __builtin_amdgcn_exp2f(q4[2] + kv[u]);
                float e3 = __builtin_amdgcn_exp2f(q4[3] + kv[u]);
                aA0 = fmaf(wa, __builtin_amdgcn_rcpf(1.0f + e0), aA0);
                aA1 = fmaf(wa, __builtin_amdgcn_rcpf(1.0f + e1), aA1);
                aB0 = fmaf(wa, __builtin_amdgcn_rcpf(1.0f + e2), aB0);
                aB1 = fmaf(wa, __builtin_amdgcn_rcpf(1.0f + e3), aB1);
            }
        }
    } else if (actB) {                    // 2-row h-loop (B rows only)
        #pragma unroll 2
        for (int h0 = 0; h0 < H_; h0 += 8) {
            float kv[8];
            #pragma unroll
            for (int u = 0; u < 8; ++u) kv[u] = k2p[(size_t)(h0 + u) * T_];
            #pragma unroll
            for (int u = 0; u < 8; ++u) {
                float wa   = Wa[h0 + u];
                float2v q2 = *(const float2v*)&qsh[(h0 + u) * 4 + 2];
                float e2 = __builtin_amdgcn_exp2f(q2[0] + kv[u]);
                float e3 = __builtin_amdgcn_exp2f(q2[1] + kv[u]);
                aB0 = fmaf(wa, __builtin_amdgcn_rcpf(1.0f + e2), aB0);
                aB1 = fmaf(wa, __builtin_amdgcn_rcpf(1.0f + e3), aB1);
            }
        }
    }

    // causal rowmax is equivalent to reference's global rowmax (it cancels in
    // p/(s+1e-7); s >= 1 since the diagonal is in the causal set).
    float eg0 = (j <= iA0) ? fmaf(-SC2, aA0, CL) : -INFINITY;
    float eg1 = (j <= iA1) ? fmaf(-SC2, aA1, CL) : -INFINITY;
    float eg2 = (j <= iB0) ? fmaf(-SC2, aB0, CL) : -INFINITY;
    float eg3 = (j <= iB1) ? fmaf(-SC2, aB1, CL) : -INFINITY;

    float M0 = eg0, M1 = eg1, M2 = eg2, M3 = eg3;
    #pragma unroll
    for (int off = 32; off; off >>= 1) {
        M0 = fmaxf(M0, __shfl_down(M0, off, 64));
        M1 = fmaxf(M1, __shfl_down(M1, off, 64));
        M2 = fmaxf(M2, __shfl_down(M2, off, 64));
        M3 = fmaxf(M3, __shfl_down(M3, off, 64));
    }
    if (lane == 0) red_m[wv] = (float4v){M0, M1, M2, M3};
    __syncthreads();                      // B1
    {
        float4v m = red_m[0];
        #pragma unroll
        for (int w = 1; w < 8; ++w) {
            float4v mw = red_m[w];
            m[0] = fmaxf(m[0], mw[0]); m[1] = fmaxf(m[1], mw[1]);
            m[2] = fmaxf(m[2], mw[2]); m[3] = fmaxf(m[3], mw[3]);
        }
        M0 = m[0]; M1 = m[1]; M2 = m[2]; M3 = m[3];
    }

    float p0 = (j <= iA0) ? __builtin_amdgcn_exp2f(eg0 - M0) : 0.0f;
    float p1 = (j <= iA1) ? __builtin_amdgcn_exp2f(eg1 - M1) : 0.0f;
    float p2 = (j <= iB0) ? __builtin_amdgcn_exp2f(eg2 - M2) : 0.0f;
    float p3 = (j <= iB1) ? __builtin_amdgcn_exp2f(eg3 - M3) : 0.0f;
    *(float4v*)&p_sh[j * 4] = (float4v){p0, p1, p2, p3};

    float S0 = p0, S1 = p1, S2 = p2, S3 = p3;
    #pragma unroll
    for (int off = 32; off; off >>= 1) {
        S0 += __shfl_down(S0, off, 64);
        S1 += __shfl_down(S1, off, 64);
        S2 += __shfl_down(S2, off, 64);
        S3 += __shfl_down(S3, off, 64);
    }
    if (lane == 0) red_s[wv] = (float4v){S0, S1, S2, S3};
    __syncthreads();                      // B2 (covers red_s and p_sh)

    float inv0, inv1, inv2, inv3;
    {
        float4v s = red_s[0];
        #pragma unroll
        for (int w = 1; w < 8; ++w) {
            float4v sw = red_s[w];
            s[0] += sw[0]; s[1] += sw[1]; s[2] += sw[2]; s[3] += sw[3];
        }
        inv0 = __builtin_amdgcn_rcpf(s[0] + 1e-7f);
        inv1 = __builtin_amdgcn_rcpf(s[1] + 1e-7f);
        inv2 = __builtin_amdgcn_rcpf(s[2] + 1e-7f);
        inv3 = __builtin_amdgcn_rcpf(s[3] + 1e-7f);
    }

    // v-phase: thread = (s-chunk of 32 j, d4 of 4 d). dwordx4 input loads,
    // b128 broadcast p reads, 16 fma per j. p==0 past each row's diagonal.
    {
        int s  = tid >> 5, d4 = tid & 31;
        float4v va0 = {0,0,0,0}, va1 = {0,0,0,0}, va2 = {0,0,0,0}, va3 = {0,0,0,0};
        if ((s << 5) <= iB1) {            // chunk has at least one unmasked j
            const float* inp = input + ((size_t)(b * T_) + (s << 5)) * D_ + (d4 << 2);
            const float* pp  = p_sh + (s << 5) * 4;
            #pragma unroll 4
            for (int jj = 0; jj < 32; ++jj) {
                float4v x  = *(const float4v*)(inp + (size_t)jj * D_);
                float4v p4 = *(const float4v*)(pp + jj * 4);
                va0 += x * p4[0];
                va1 += x * p4[1];
                va2 += x * p4[2];
                va3 += x * p4[3];
            }
        }
        *(float4v*)&partial[s][0 * D_ + (d4 << 2)] = va0;
        *(float4v*)&partial[s][1 * D_ + (d4 << 2)] = va1;
        *(float4v*)&partial[s][2 * D_ + (d4 << 2)] = va2;
        *(float4v*)&partial[s][3 * D_ + (d4 << 2)] = va3;
    }
    __syncthreads();                      // B3

    {
        int r  = tid >> 7, d = tid & 127;
        float v = 0.f;
        #pragma unroll
        for (int ss = 0; ss < 16; ++ss) v += partial[ss][r * D_ + d];
        int   ir  = (r < 2) ? (iA0 + r) : (iB0 + r - 2);
        float inv = (r == 0) ? inv0 : (r == 1) ? inv1 : (r == 2) ? inv2 : inv3;
        out_v[(size_t)(b * T_ + ir) * D_ + d] = v * inv;
    }

    // e-writes last: no barrier after, stores drain at kernel end
    out_e[((size_t)(b * T_ + iA0)) * T_ + j] = p0 * inv0;
    out_e[((size_t)(b * T_ + iA1)) * T_ + j] = p1 * inv1;
    out_e[((size_t)(b * T_ + iB0)) * T_ + j] = p2 * inv2;
    out_e[((size_t)(b * T_ + iB1)) * T_ + j] = p3 * inv3;
}

extern "C" void kernel_launch(void* const* d_in, const int* in_sizes, int n_in,
                              void* d_out, int out_size, void* d_ws, size_t ws_size,
                              hipStream_t stream)
{
    const float* input = (const float*)d_in[0];
    const float* demo  = (const float*)d_in[1];
    const float* Wt    = (const float*)d_in[2];
    const float* Wx    = (const float*)d_in[3];
    const float* Wd    = (const float*)d_in[4];
    const float* bh    = (const float*)d_in[5];
    const float* Wa    = (const float*)d_in[6];
    const float* ba    = (const float*)d_in[7];

    float* out_v = (float*)d_out;                     // [B,T,D]
    float* out_e = out_v + (size_t)B_ * T_ * D_;      // [B,T,T]

    float* Q   = (float*)d_ws;                        // [B*T, H]  (pre-scaled)
    float* K2T = Q + (size_t)B_ * T_ * H_;            // [B, H, T] (pre-scaled)
    float* Cs  = K2T + (size_t)B_ * H_ * T_;          // [1]

    prep_kernel<<<dim3(B_ * T_ / 8), 256, 0, stream>>>(input, demo, Wt, Wx, Wd, bh,
                                                       Wa, ba, Q, K2T, Cs);
    attn_kernel<<<dim3(128, B_), 512, 0, stream>>>(input, Q, K2T, Wa, Cs, out_v, out_e);
}